// Round 12
// baseline (79.884 us; speedup 1.0000x reference)
//
#include <hip/hip_runtime.h>
#include <hip/hip_bf16.h>
#include <math.h>

// Problem constants (fixed by setup_inputs)
#define BB 2
#define NN 4096
#define MM 4096
#define DD 64

#define NSPLIT 8
#define MRANGE (MM / NSPLIT)   // 512 m per block
#define BMT 64                 // m per M-step
#define NSTEP (MRANGE / BMT)   // 8
#define BLK_N 128              // n rows per block (8 waves x 16)
#define NBLK_B (NN / BLK_N)    // 32 n-blocks per batch

typedef __attribute__((ext_vector_type(8))) short bf16x8;   // 8 bf16 (4 VGPRs)
typedef __attribute__((ext_vector_type(4))) float f32x4;

#define FEAT_BLOCKS ((BB * (NN + MM)) / 4)    // 4096
#define COORD_BLOCKS ((BB * (NN + MM)) / 256) // 64

// ---------------------------------------------------------------------------
// Fused prep: (a) L2-normalize features; source rows -> [hi|lo] bf16 split
//   (fs2, 128/row); target rows -> hi-only DENSE array (fth, 64/row, 1 MB).
// (b) coordinate float4 tables {x,y,z,|c|^2}.
// ---------------------------------------------------------------------------
__global__ __launch_bounds__(256) void prep_all(const float* __restrict__ fs,
                                                const float* __restrict__ ft,
                                                const float* __restrict__ cs,
                                                const float* __restrict__ ct,
                                                unsigned short* __restrict__ fs2,
                                                unsigned short* __restrict__ fth,
                                                float4* __restrict__ cs4,
                                                float4* __restrict__ ct4) {
    int bid = blockIdx.x;
    if (bid < FEAT_BLOCKS) {
        int row  = bid * 4 + (threadIdx.x >> 6);   // 4 waves per block
        int lane = threadIdx.x & 63;
        if (row < BB * NN) {
            float x = fs[(size_t)row * DD + lane];
            float s = x * x;
            #pragma unroll
            for (int o = 32; o > 0; o >>= 1) s += __shfl_xor(s, o, 64);
            float xn = x / sqrtf(s);
            __hip_bfloat16 h = __float2bfloat16(xn);
            float hf = __bfloat162float(h);
            __hip_bfloat16 l = __float2bfloat16(xn - hf);
            fs2[(size_t)row * 128 + lane]      = *(unsigned short*)&h;
            fs2[(size_t)row * 128 + 64 + lane] = *(unsigned short*)&l;
        } else {
            int r = row - BB * NN;
            float x = ft[(size_t)r * DD + lane];
            float s = x * x;
            #pragma unroll
            for (int o = 32; o > 0; o >>= 1) s += __shfl_xor(s, o, 64);
            float xn = x / sqrtf(s);
            __hip_bfloat16 h = __float2bfloat16(xn);
            fth[(size_t)r * 64 + lane] = *(unsigned short*)&h;
        }
    } else {
        int i = (bid - FEAT_BLOCKS) * 256 + threadIdx.x;   // over BB*(NN+MM) pts
        const float* c; float4* d;
        if (i < BB * NN) { c = cs + (size_t)i * 3; d = cs4 + i; }
        else { int r = i - BB * NN; c = ct + (size_t)r * 3; d = ct4 + r; }
        float x = c[0], y = c[1], z = c[2];
        *d = make_float4(x, y, z, x * x + y * y + z * z);
    }
}

// ---------------------------------------------------------------------------
// Main: MFMA pair kernel — R11 dataflow, re-cut as 8 waves x 16 n-rows.
// Same 512-block grid, same per-block tile (128 n x 512 m), same LDS (16 KB),
// but 512 threads/block -> 16 waves/CU = 4 waves/SIMD (R11 was 2/SIMD and
// grid-limited). Per wave: one A-frag set (4 x bf16x8), one C-tile/subtile
// (4 MFMA), 4-row epilogue. Numerics identical to R11 (absmax 0.0):
//   dot = (hi_s + lo_s) . hi_t ; mask st3 > thr[i] + 0.5*cv.w.
// launch_bounds (512,2): cap 128 VGPR; natural usage ~90 -> no spill
// (R6 lesson: cap below natural => scratch catastrophe; here it is above).
// ---------------------------------------------------------------------------
__global__ __launch_bounds__(512, 2) void flow_mfma(
    const unsigned short* __restrict__ fs2, const unsigned short* __restrict__ fth,
    const float4* __restrict__ cs4, const float4* __restrict__ ct4,
    const float* __restrict__ eps, float4* __restrict__ part) {

    __shared__ unsigned short ftl[2][BMT * 64];   // 2 x 8 KB (hi half only)

    const int t    = threadIdx.x;
    const int lane = t & 63;
    const int w    = t >> 6;        // wave 0..7
    const int l15  = lane & 15;
    const int g    = lane >> 4;     // 16-lane group 0..3

    const int bidx  = blockIdx.x;   // 0 .. BB*NBLK_B-1 (64)
    const int split = blockIdx.y;   // 0 .. NSPLIT-1
    const int b   = bidx >> 5;      // NBLK_B = 32
    const int n0w = (bidx & 31) * BLK_N + w * 16;
    const int m0s = split * MRANGE;

    // w = exp(-(2-2*dot)/tau) = exp2((dot-1)*k2)
    const float k2 = 2.0f * 1.44269504f / (__expf(eps[0]) + 0.03f);

    // Hoist A-fragments: wave's 16 fs2 rows, K=128 in 4 chunks of 32
    // (chunks 0,1 = hi dims; 2,3 = lo dims).
    // A layout (16x16x32): row = lane&15, k-chunk slot = lane>>4.
    bf16x8 aA[4];
    {
        const unsigned short* arowA = fs2 + ((size_t)b * NN + n0w + l15) * 128;
        #pragma unroll
        for (int c = 0; c < 4; ++c)
            aA[c] = *(const bf16x8*)(arowA + c * 32 + g * 8);
    }
    // Hoist cs: n = n0w + 4g + r.
    // thr = 0.5*(|cs|^2 - 100): mask d2<100 <=> st3 > thr + 0.5*|ct|^2
    float sx[4], sy[4], sz[4], thr[4];
    #pragma unroll
    for (int r = 0; r < 4; ++r) {
        float4 v = cs4[(size_t)b * NN + n0w + 4 * g + r];
        sx[r] = v.x; sy[r] = v.y; sz[r] = v.z; thr[r] = 0.5f * (v.w - 100.0f);
    }

    float accx[4] = {0.f,0.f,0.f,0.f}, accy[4] = {0.f,0.f,0.f,0.f};
    float accz[4] = {0.f,0.f,0.f,0.f}, accw[4] = {0.f,0.f,0.f,0.f};

    const unsigned short* fthb = fth + (size_t)b * MM * 64;
    const float4* ctb = ct4 + (size_t)b * MM;

    // stage: 1 global_load_lds(16B) per thread (512 granules = 64 rows x 128B);
    // LDS dest linear, global source pre-swizzled (q ^ (m&7)) so the swizzled
    // READ is conflict-free (rule 21; measured 0 conflicts since R8).
    auto STAGE = [&](int buf, int step) {
        const int m0 = m0s + step * BMT;
        int idx = t;                                 // 16B granule 0..511
        int m   = idx >> 3;                          // row 0..63
        int q   = idx & 7;                           // granule within row
        int sg  = q ^ (m & 7);                       // inverse swizzle on src
        const unsigned short* src = fthb + (size_t)(m0 + m) * 64 + sg * 8;
        unsigned short* dst = (unsigned short*)&ftl[buf][(size_t)idx * 8];
        __builtin_amdgcn_global_load_lds(
            (const __attribute__((address_space(1))) void*)src,
            (__attribute__((address_space(3))) void*)dst, 16, 0, 0);
    };

    int cur = 0;
    STAGE(0, 0);

    for (int step = 0; step < NSTEP; ++step) {
        if (step + 1 < NSTEP) {
            STAGE(cur ^ 1, step + 1);
            asm volatile("s_waitcnt vmcnt(1)" ::: "memory");   // cur's load done, next in flight
        } else {
            asm volatile("s_waitcnt vmcnt(0)" ::: "memory");
        }
        __builtin_amdgcn_s_barrier();
        asm volatile("" ::: "memory");

        const int m0 = m0s + step * BMT;
        // prefetch this step's 4 coordinate vectors up-front (L2 latency hides
        // under the first subtile's MFMAs)
        float4 cv4[4];
        #pragma unroll
        for (int st = 0; st < 4; ++st)
            cv4[st] = ctb[m0 + st * 16 + l15];

        #pragma unroll
        for (int st = 0; st < 4; ++st) {
            const int mloc = st * 16 + l15;              // this lane's m column
            const float4 cv = cv4[st];

            // B-frags (hi chunks): col = lane&15 = m, granule swizzled by row
            bf16x8 bf0 = *(const bf16x8*)&ftl[cur][(size_t)mloc * 64 + (((0 * 4 + g) ^ (mloc & 7)) * 8)];
            bf16x8 bf1 = *(const bf16x8*)&ftl[cur][(size_t)mloc * 64 + (((1 * 4 + g) ^ (mloc & 7)) * 8)];

            f32x4 CA = {0.f, 0.f, 0.f, 0.f};
            // hi_s.hi_t
            CA = __builtin_amdgcn_mfma_f32_16x16x32_bf16(aA[0], bf0, CA, 0, 0, 0);
            CA = __builtin_amdgcn_mfma_f32_16x16x32_bf16(aA[1], bf1, CA, 0, 0, 0);
            // lo_s.hi_t
            CA = __builtin_amdgcn_mfma_f32_16x16x32_bf16(aA[2], bf0, CA, 0, 0, 0);
            CA = __builtin_amdgcn_mfma_f32_16x16x32_bf16(aA[3], bf1, CA, 0, 0, 0);

            const float thrc = 0.5f * cv.w;
            #pragma unroll
            for (int r = 0; r < 4; ++r) {
                const float dotv = CA[r];
                float st3 = fmaf(sx[r], cv.x, fmaf(sy[r], cv.y, sz[r] * cv.z));
                float arg = fmaf(dotv, k2, -k2);
                float argm = (st3 > thr[r] + thrc) ? arg : -500.0f;  // exp2(-500)=0
                float wgt = exp2f(argm);
                accx[r] = fmaf(wgt, cv.x, accx[r]);
                accy[r] = fmaf(wgt, cv.y, accy[r]);
                accz[r] = fmaf(wgt, cv.z, accz[r]);
                accw[r] += wgt;
            }
        }
        __builtin_amdgcn_s_barrier();
        asm volatile("" ::: "memory");
        cur ^= 1;
    }

    // reduce across the 16 lanes of each group (same n set, different m)
    #pragma unroll
    for (int r = 0; r < 4; ++r) {
        #pragma unroll
        for (int o = 1; o < 16; o <<= 1) {
            accx[r] += __shfl_xor(accx[r], o, 16);
            accy[r] += __shfl_xor(accy[r], o, 16);
            accz[r] += __shfl_xor(accz[r], o, 16);
            accw[r] += __shfl_xor(accw[r], o, 16);
        }
    }
    if (l15 == 0) {
        #pragma unroll
        for (int r = 0; r < 4; ++r) {
            int n = n0w + 4 * g + r;
            part[((size_t)split * BB + b) * NN + n] =
                make_float4(accx[r], accy[r], accz[r], accw[r]);
        }
    }
}

// ---------------------------------------------------------------------------
// Finish: combine splits, normalize, subtract coor_s
// ---------------------------------------------------------------------------
__global__ __launch_bounds__(256) void finish_kernel(const float4* __restrict__ part,
                                                     const float* __restrict__ cs,
                                                     float* __restrict__ out) {
    int idx = blockIdx.x * 256 + threadIdx.x;   // b*NN + n
    if (idx >= BB * NN) return;
    float x = 0.f, y = 0.f, z = 0.f, w = 0.f;
    #pragma unroll
    for (int s = 0; s < NSPLIT; ++s) {
        const float4 v = part[(size_t)s * BB * NN + idx];
        x += v.x; y += v.y; z += v.z; w += v.w;
    }
    const float den = w + 1e-8f;
    out[(size_t)idx * 3 + 0] = x / den - cs[(size_t)idx * 3 + 0];
    out[(size_t)idx * 3 + 1] = y / den - cs[(size_t)idx * 3 + 1];
    out[(size_t)idx * 3 + 2] = z / den - cs[(size_t)idx * 3 + 2];
}

extern "C" void kernel_launch(void* const* d_in, const int* in_sizes, int n_in,
                              void* d_out, int out_size, void* d_ws, size_t ws_size,
                              hipStream_t stream) {
    const float* feat_s = (const float*)d_in[0];
    const float* feat_t = (const float*)d_in[1];
    const float* coor_s = (const float*)d_in[2];
    const float* coor_t = (const float*)d_in[3];
    const float* eps    = (const float*)d_in[4];
    float* out = (float*)d_out;

    // workspace layout: fs2 2MB | fth 1MB | cs4 128KB | ct4 128KB | part 1MB
    unsigned short* fs2 = (unsigned short*)d_ws;
    unsigned short* fth = fs2 + (size_t)BB * NN * 128;
    float4* cs4  = (float4*)(fth + (size_t)BB * MM * 64);
    float4* ct4  = cs4 + (size_t)BB * NN;
    float4* part = ct4 + (size_t)BB * MM;

    prep_all<<<FEAT_BLOCKS + COORD_BLOCKS, 256, 0, stream>>>(
        feat_s, feat_t, coor_s, coor_t, fs2, fth, cs4, ct4);

    flow_mfma<<<dim3(BB * NBLK_B, NSPLIT), 512, 0, stream>>>(
        fs2, fth, cs4, ct4, eps, part);

    finish_kernel<<<(BB * NN + 255) / 256, 256, 0, stream>>>(part, coor_s, out);
}

// Round 13
// 37.583 us; speedup vs baseline: 2.1255x; 2.1255x over previous
//
#include <hip/hip_runtime.h>
#include <hip/hip_bf16.h>
#include <math.h>

// Problem constants (fixed by setup_inputs)
#define BB 2
#define NN 4096
#define MM 4096
#define DD 64

#define NSPLIT 8
#define MRANGE (MM / NSPLIT)   // 512 m per wave sweep
#define NSUBT (MRANGE / 16)    // 32 subtiles of 16 m
#define NBLK_B (NN / 64)       // 64 n-blocks per batch (block = 4 waves x 16 rows)

typedef __attribute__((ext_vector_type(8))) short bf16x8;   // 8 bf16 (4 VGPRs)
typedef __attribute__((ext_vector_type(4))) float f32x4;

#define FEAT_BLOCKS ((BB * (NN + MM)) / 4)    // 4096
#define COORD_BLOCKS ((BB * (NN + MM)) / 256) // 64

// ---------------------------------------------------------------------------
// Fused prep:
// (a) source rows -> L2-normalize, [hi|lo] bf16 split (fs2, 128/row).
// (b) target rows -> hi-only TRANSPOSED-GRANULE layout fthT:
//       fthT[(mg*8 + g')*128 + (m&15)*8 + j] = hi(ft_norm[m][g'*8+j])
//     so a 16-lane group's B-fragment read (one granule g', 16 m) is a single
//     contiguous 256B segment -> fully coalesced wave loads in flow (fixes
//     R9's address-divergence, which was that round's failure mode).
// (c) coordinate float4 tables {x,y,z,|c|^2}.
// ---------------------------------------------------------------------------
__global__ __launch_bounds__(256) void prep_all(const float* __restrict__ fs,
                                                const float* __restrict__ ft,
                                                const float* __restrict__ cs,
                                                const float* __restrict__ ct,
                                                unsigned short* __restrict__ fs2,
                                                unsigned short* __restrict__ fthT,
                                                float4* __restrict__ cs4,
                                                float4* __restrict__ ct4) {
    int bid = blockIdx.x;
    if (bid < FEAT_BLOCKS) {
        int row  = bid * 4 + (threadIdx.x >> 6);   // 4 waves per block
        int lane = threadIdx.x & 63;
        if (row < BB * NN) {
            float x = fs[(size_t)row * DD + lane];
            float s = x * x;
            #pragma unroll
            for (int o = 32; o > 0; o >>= 1) s += __shfl_xor(s, o, 64);
            float xn = x / sqrtf(s);
            __hip_bfloat16 h = __float2bfloat16(xn);
            float hf = __bfloat162float(h);
            __hip_bfloat16 l = __float2bfloat16(xn - hf);
            fs2[(size_t)row * 128 + lane]      = *(unsigned short*)&h;
            fs2[(size_t)row * 128 + 64 + lane] = *(unsigned short*)&l;
        } else {
            int r = row - BB * NN;                 // global target row (b*MM + m)
            float x = ft[(size_t)r * DD + lane];
            float s = x * x;
            #pragma unroll
            for (int o = 32; o > 0; o >>= 1) s += __shfl_xor(s, o, 64);
            float xn = x / sqrtf(s);
            __hip_bfloat16 h = __float2bfloat16(xn);
            unsigned short hv = *(unsigned short*)&h;
            // pack 8 halfwords (dims (lane>>3)*8 .. +7) into lanes with lane&7==0
            bf16x8 pk;
            #pragma unroll
            for (int j = 0; j < 8; ++j)
                pk[j] = (short)__shfl((int)hv, (lane & 56) + j, 64);
            if ((lane & 7) == 0) {
                // granule g' = lane>>3 ; mg = r>>4 (batch offset folds in: MM%16==0)
                size_t off = ((size_t)(r >> 4) * 8 + (lane >> 3)) * 128 + (size_t)(r & 15) * 8;
                *(bf16x8*)&fthT[off] = pk;
            }
        }
    } else {
        int i = (bid - FEAT_BLOCKS) * 256 + threadIdx.x;   // over BB*(NN+MM) pts
        const float* c; float4* d;
        if (i < BB * NN) { c = cs + (size_t)i * 3; d = cs4 + i; }
        else { int r = i - BB * NN; c = ct + (size_t)r * 3; d = ct4 + r; }
        float x = c[0], y = c[1], z = c[2];
        *d = make_float4(x, y, z, x * x + y * y + z * z);
    }
}

// ---------------------------------------------------------------------------
// Main: MFMA pair kernel — NO LDS, NO BARRIERS, coalesced B loads.
// Numerics identical to R11 (absmax 0.0): dot = (hi_s+lo_s).hi_t;
// mask st3 > thr[r] + 0.5*cv.w  <=>  d2 < 100.
// Block = 4 fully independent waves; wave owns 16 n-rows (A-frags + cs in
// registers, ~80 VGPR) and sweeps 512 m as 32 subtiles. Per subtile:
//   2 coalesced 1KB wave-loads (bf0,bf1 from fthT), 1 coalesced cv load,
//   4 MFMA, 4-row epilogue. Waves drift freely; 4 blocks/CU, 4 waves/SIMD.
// launch_bounds (256,2): cap 256 — NEVER cap below natural need (R6/R12:
// caps of 128 forced scratch spills, FETCH/WRITE explosions).
// ---------------------------------------------------------------------------
__global__ __launch_bounds__(256, 2) void flow_mfma(
    const unsigned short* __restrict__ fs2, const unsigned short* __restrict__ fthT,
    const float4* __restrict__ cs4, const float4* __restrict__ ct4,
    const float* __restrict__ eps, float4* __restrict__ part) {

    const int t    = threadIdx.x;
    const int lane = t & 63;
    const int w    = t >> 6;        // wave 0..3
    const int l15  = lane & 15;
    const int g    = lane >> 4;     // 16-lane group 0..3

    const int bidx  = blockIdx.x;   // 0 .. BB*NBLK_B-1 (128)
    const int split = blockIdx.y;   // 0 .. NSPLIT-1
    const int b   = bidx >> 6;      // NBLK_B = 64
    const int n0w = (bidx & 63) * 64 + w * 16;
    const int m0s = split * MRANGE;

    // w = exp(-(2-2*dot)/tau) = exp2((dot-1)*k2)
    const float k2 = 2.0f * 1.44269504f / (__expf(eps[0]) + 0.03f);

    // Hoist A-fragments: wave's 16 fs2 rows, K=128 in 4 chunks of 32
    // (chunks 0,1 = hi dims; 2,3 = lo dims).
    bf16x8 aA[4];
    {
        const unsigned short* arowA = fs2 + ((size_t)b * NN + n0w + l15) * 128;
        #pragma unroll
        for (int c = 0; c < 4; ++c)
            aA[c] = *(const bf16x8*)(arowA + c * 32 + g * 8);
    }
    // Hoist cs: n = n0w + 4g + r.
    float sx[4], sy[4], sz[4], thr[4];
    #pragma unroll
    for (int r = 0; r < 4; ++r) {
        float4 v = cs4[(size_t)b * NN + n0w + 4 * g + r];
        sx[r] = v.x; sy[r] = v.y; sz[r] = v.z; thr[r] = 0.5f * (v.w - 100.0f);
    }

    float accx[4] = {0.f,0.f,0.f,0.f}, accy[4] = {0.f,0.f,0.f,0.f};
    float accz[4] = {0.f,0.f,0.f,0.f}, accw[4] = {0.f,0.f,0.f,0.f};

    const unsigned short* fthTb = fthT + (size_t)b * MM * 64;
    const float4* ctb = ct4 + (size_t)b * MM;

    #pragma unroll 4
    for (int st = 0; st < NSUBT; ++st) {
        const int m0 = m0s + st * 16;
        const int mg = m0 >> 4;
        const unsigned short* seg = fthTb + (size_t)mg * 1024;   // 8 granules x 128

        // B-frags: granule g (dims g*8..) and granule 4+g (dims 32+g*8..);
        // 16 lanes of a group read 16 consecutive 16B slots -> coalesced.
        bf16x8 bf0 = *(const bf16x8*)(seg + (size_t)g * 128 + l15 * 8);
        bf16x8 bf1 = *(const bf16x8*)(seg + (size_t)(4 + g) * 128 + l15 * 8);
        float4 cv  = ctb[m0 + l15];

        f32x4 CA = {0.f, 0.f, 0.f, 0.f};
        // hi_s.hi_t
        CA = __builtin_amdgcn_mfma_f32_16x16x32_bf16(aA[0], bf0, CA, 0, 0, 0);
        CA = __builtin_amdgcn_mfma_f32_16x16x32_bf16(aA[1], bf1, CA, 0, 0, 0);
        // lo_s.hi_t
        CA = __builtin_amdgcn_mfma_f32_16x16x32_bf16(aA[2], bf0, CA, 0, 0, 0);
        CA = __builtin_amdgcn_mfma_f32_16x16x32_bf16(aA[3], bf1, CA, 0, 0, 0);

        const float thrc = 0.5f * cv.w;
        #pragma unroll
        for (int r = 0; r < 4; ++r) {
            float st3 = fmaf(sx[r], cv.x, fmaf(sy[r], cv.y, sz[r] * cv.z));
            float arg = fmaf(CA[r], k2, -k2);
            float argm = (st3 > thr[r] + thrc) ? arg : -500.0f;  // exp2(-500)=0
            float wgt = exp2f(argm);
            accx[r] = fmaf(wgt, cv.x, accx[r]);
            accy[r] = fmaf(wgt, cv.y, accy[r]);
            accz[r] = fmaf(wgt, cv.z, accz[r]);
            accw[r] += wgt;
        }
    }

    // reduce across the 16 lanes of each group (same n set, different m)
    #pragma unroll
    for (int r = 0; r < 4; ++r) {
        #pragma unroll
        for (int o = 1; o < 16; o <<= 1) {
            accx[r] += __shfl_xor(accx[r], o, 16);
            accy[r] += __shfl_xor(accy[r], o, 16);
            accz[r] += __shfl_xor(accz[r], o, 16);
            accw[r] += __shfl_xor(accw[r], o, 16);
        }
    }
    if (l15 == 0) {
        #pragma unroll
        for (int r = 0; r < 4; ++r) {
            int n = n0w + 4 * g + r;
            part[((size_t)split * BB + b) * NN + n] =
                make_float4(accx[r], accy[r], accz[r], accw[r]);
        }
    }
}

// ---------------------------------------------------------------------------
// Finish: combine splits, normalize, subtract coor_s
// ---------------------------------------------------------------------------
__global__ __launch_bounds__(256) void finish_kernel(const float4* __restrict__ part,
                                                     const float* __restrict__ cs,
                                                     float* __restrict__ out) {
    int idx = blockIdx.x * 256 + threadIdx.x;   // b*NN + n
    if (idx >= BB * NN) return;
    float x = 0.f, y = 0.f, z = 0.f, w = 0.f;
    #pragma unroll
    for (int s = 0; s < NSPLIT; ++s) {
        const float4 v = part[(size_t)s * BB * NN + idx];
        x += v.x; y += v.y; z += v.z; w += v.w;
    }
    const float den = w + 1e-8f;
    out[(size_t)idx * 3 + 0] = x / den - cs[(size_t)idx * 3 + 0];
    out[(size_t)idx * 3 + 1] = y / den - cs[(size_t)idx * 3 + 1];
    out[(size_t)idx * 3 + 2] = z / den - cs[(size_t)idx * 3 + 2];
}

extern "C" void kernel_launch(void* const* d_in, const int* in_sizes, int n_in,
                              void* d_out, int out_size, void* d_ws, size_t ws_size,
                              hipStream_t stream) {
    const float* feat_s = (const float*)d_in[0];
    const float* feat_t = (const float*)d_in[1];
    const float* coor_s = (const float*)d_in[2];
    const float* coor_t = (const float*)d_in[3];
    const float* eps    = (const float*)d_in[4];
    float* out = (float*)d_out;

    // workspace layout: fs2 2MB | fthT 1MB | cs4 128KB | ct4 128KB | part 1MB
    unsigned short* fs2  = (unsigned short*)d_ws;
    unsigned short* fthT = fs2 + (size_t)BB * NN * 128;
    float4* cs4  = (float4*)(fthT + (size_t)BB * MM * 64);
    float4* ct4  = cs4 + (size_t)BB * NN;
    float4* part = ct4 + (size_t)BB * MM;

    prep_all<<<FEAT_BLOCKS + COORD_BLOCKS, 256, 0, stream>>>(
        feat_s, feat_t, coor_s, coor_t, fs2, fthT, cs4, ct4);

    flow_mfma<<<dim3(BB * NBLK_B, NSPLIT), 256, 0, stream>>>(
        fs2, fthT, cs4, ct4, eps, part);

    finish_kernel<<<(BB * NN + 255) / 256, 256, 0, stream>>>(part, coor_s, out);
}